// Round 11
// baseline (546.470 us; speedup 1.0000x reference)
//
#include <hip/hip_runtime.h>

#define D 128
#define B 256
#define NPB 64          // nodes per bin (bin LDS tile = 64*128*4B = 32 KB)
#define BIN_SHIFT 6
#define MAXBINS 1024
#define CAPB 1280       // per-bin capacity; mean 767, sigma 28 -> +18 sigma
#define CHA 4096        // edges per pass-A block
#define EPT 16          // edges per thread in pass A (CHA / B)
#define SPILL_MAX 8192

typedef float vfloat4 __attribute__((ext_vector_type(4)));

// ---------------------------------------------------------------------------
// GCN message passing via LDS-tile scatter (no edge grouping at all):
//   prep   : gcur=0, out2=x (NT), xb=bf16(x)
//   bucketA: partition edges into 782 bins of 64 dest-nodes; dense ordered
//            append (LDS classify + prefix + one global cursor per bin).
//   deg    : per-bin LDS histogram of dest -> dis[node]=rsqrt(deg+1)
//   aggB   : per-bin 32KB LDS accumulator; waves gather w*xb[src] rows and
//            LDS-atomic-add; dense writeout out = bias + dc*(acc + dc*xc).
//   Spill list handles bin overflow (statistically never; correctness-safe).
// Fallback (small ws): round-4 CSR-pairs pipeline (known good).
// ---------------------------------------------------------------------------

__device__ __forceinline__ unsigned short f2bf(float f) {   // RTNE f32->bf16
    unsigned u = __float_as_uint(f);
    u = u + 0x7FFFu + ((u >> 16) & 1u);
    return (unsigned short)(u >> 16);
}
__device__ __forceinline__ float bflo(unsigned u) { return __uint_as_float(u << 16); }
__device__ __forceinline__ float bfhi(unsigned u) { return __uint_as_float(u & 0xffff0000u); }

__device__ __forceinline__ vfloat4 bf2f4(unsigned lo, unsigned hi) {
    vfloat4 r;
    r.x = bflo(lo); r.y = bfhi(lo); r.z = bflo(hi); r.w = bfhi(hi);
    return r;
}

__global__ void k_prep(const float* __restrict__ x, float* __restrict__ out2,
                       uint2* __restrict__ xb, int* __restrict__ gcur,
                       int* __restrict__ spillCnt, int n, int nbins) {
    int gid = blockIdx.x * blockDim.x + threadIdx.x;
    if (gid == 0) *spillCnt = 0;
    if (gid < nbins) gcur[gid] = 0;
    if (gid >= n * 32) return;
    vfloat4 xv = reinterpret_cast<const vfloat4*>(x)[gid];
    __builtin_nontemporal_store(xv, reinterpret_cast<vfloat4*>(out2) + gid);
    uint2 b;
    b.x = (unsigned)f2bf(xv.x) | ((unsigned)f2bf(xv.y) << 16);
    b.y = (unsigned)f2bf(xv.z) | ((unsigned)f2bf(xv.w) << 16);
    xb[gid] = b;
}

// Pass A: each block partitions CHA edges into bins, appends densely to gbin.
__global__ void k_bucketA(const int* __restrict__ row, const int* __restrict__ col,
                          long long* __restrict__ gbin, int* __restrict__ gcur,
                          long long* __restrict__ spill, int* __restrict__ spillCnt,
                          int e, int nbins) {
    __shared__ int cnt[MAXBINS];
    __shared__ int basep[MAXBINS];
    __shared__ int gbs[MAXBINS];
    __shared__ int tsum[B];
    __shared__ long long buf[CHA];     // 32 KB
    __shared__ int nvS;

    int t = threadIdx.x;
    for (int i = t; i < MAXBINS; i += B) cnt[i] = 0;
    __syncthreads();

    int rs[EPT], cs[EPT], lp[EPT];
    int base = blockIdx.x * CHA + t * EPT;
    bool fast = (base + EPT <= e) &&
                ((((uintptr_t)(row + base) | (uintptr_t)(col + base)) & 15) == 0);
    if (fast) {
#pragma unroll
        for (int k = 0; k < EPT / 4; ++k) {
            int4 r4 = reinterpret_cast<const int4*>(row + base)[k];
            int4 c4 = reinterpret_cast<const int4*>(col + base)[k];
            rs[4*k+0] = r4.x; rs[4*k+1] = r4.y; rs[4*k+2] = r4.z; rs[4*k+3] = r4.w;
            cs[4*k+0] = c4.x; cs[4*k+1] = c4.y; cs[4*k+2] = c4.z; cs[4*k+3] = c4.w;
        }
    } else {
#pragma unroll
        for (int k = 0; k < EPT; ++k) {
            int i = base + k;
            rs[k] = (i < e) ? row[i] : -1;
            cs[k] = (i < e) ? col[i] : 0;
        }
    }
#pragma unroll
    for (int k = 0; k < EPT; ++k) {
        lp[k] = (rs[k] >= 0) ? atomicAdd(&cnt[cs[k] >> BIN_SHIFT], 1) : -1;
    }
    __syncthreads();

    // prefix over MAXBINS: per-thread chunk of 4 bins, then LDS scan of 256
    int s0 = cnt[4*t], s1 = cnt[4*t+1], s2 = cnt[4*t+2], s3 = cnt[4*t+3];
    int s = s0 + s1 + s2 + s3;
    tsum[t] = s;
    __syncthreads();
    for (int st = 1; st < B; st <<= 1) {
        int v = (t >= st) ? tsum[t - st] : 0;
        __syncthreads();
        tsum[t] += v;
        __syncthreads();
    }
    int run = tsum[t] - s;
    if (t == B - 1) nvS = tsum[t];
    basep[4*t]   = run; run += s0;
    basep[4*t+1] = run; run += s1;
    basep[4*t+2] = run; run += s2;
    basep[4*t+3] = run;
    __syncthreads();

    // reserve global space per bin + scatter into ordered LDS buffer
    for (int i = t; i < nbins; i += B)
        if (cnt[i] > 0) gbs[i] = atomicAdd(&gcur[i], cnt[i]);
#pragma unroll
    for (int k = 0; k < EPT; ++k) {
        if (lp[k] < 0) continue;
        int bin = cs[k] >> BIN_SHIFT;
        buf[basep[bin] + lp[k]] = ((long long)rs[k] << 32) | (unsigned)cs[k];
    }
    __syncthreads();

    // coalesced copy-out
    int nv = nvS;
    for (int i = t; i < nv; i += B) {
        long long ll = buf[i];
        int c = (int)(unsigned)ll;
        int bin = c >> BIN_SHIFT;
        int g = gbs[bin] + (i - basep[bin]);
        if (g < CAPB) {
            gbin[(size_t)bin * CAPB + g] = ll;
        } else {
            int sl = atomicAdd(spillCnt, 1);
            if (sl < SPILL_MAX) spill[sl] = ll;
        }
    }
}

// Per-bin degree histogram -> dis
__global__ void k_deg(const long long* __restrict__ gbin, const int* __restrict__ gcur,
                      const long long* __restrict__ spill, const int* __restrict__ spillCnt,
                      float* __restrict__ dis, int n) {
    __shared__ int hist[NPB];
    int b = blockIdx.x, t = threadIdx.x;
    if (t < NPB) hist[t] = 0;
    __syncthreads();
    int cb = min(gcur[b], CAPB);
    const long long* bb = gbin + (size_t)b * CAPB;
    for (int i = t; i < cb; i += B) {
        int c = (int)(unsigned)bb[i];
        atomicAdd(&hist[c & (NPB - 1)], 1);
    }
    int sc = min(*spillCnt, SPILL_MAX);
    for (int i = t; i < sc; i += B) {
        int c = (int)(unsigned)spill[i];
        if ((c >> BIN_SHIFT) == b) atomicAdd(&hist[c & (NPB - 1)], 1);
    }
    __syncthreads();
    int node = b * NPB + t;
    if (t < NPB && node < n) dis[node] = rsqrtf((float)hist[t] + 1.0f);
}

// Per-bin LDS accumulate + dense writeout.
__global__ void k_aggB(const uint2* __restrict__ xb, const float* __restrict__ bias,
                       const float* __restrict__ dis,
                       const long long* __restrict__ gbin, const int* __restrict__ gcur,
                       const long long* __restrict__ spill, const int* __restrict__ spillCnt,
                       float* __restrict__ out, int n) {
    __shared__ float acc[NPB * D];     // 32 KB
    int b = blockIdx.x, t = threadIdx.x;
    vfloat4 z = {0.f, 0.f, 0.f, 0.f};
    for (int i = t; i < NPB * D / 4; i += B)
        reinterpret_cast<vfloat4*>(acc)[i] = z;
    __syncthreads();

    int cb = min(gcur[b], CAPB);
    const long long* bb = gbin + (size_t)b * CAPB;
    const unsigned* xbu = reinterpret_cast<const unsigned*>(xb);
    int wid = t >> 6, q = t & 63;

    int j = wid;
    for (; j + 12 < cb; j += 16) {
        long long l0 = bb[j], l1 = bb[j + 4], l2 = bb[j + 8], l3 = bb[j + 12];
        int r0 = (int)(l0 >> 32), c0 = (int)(unsigned)l0;
        int r1 = (int)(l1 >> 32), c1 = (int)(unsigned)l1;
        int r2 = (int)(l2 >> 32), c2 = (int)(unsigned)l2;
        int r3 = (int)(l3 >> 32), c3 = (int)(unsigned)l3;
        unsigned u0 = xbu[(size_t)r0 * 64 + q];
        unsigned u1 = xbu[(size_t)r1 * 64 + q];
        unsigned u2 = xbu[(size_t)r2 * 64 + q];
        unsigned u3 = xbu[(size_t)r3 * 64 + q];
        float w0 = dis[r0], w1 = dis[r1], w2 = dis[r2], w3 = dis[r3];
        atomicAdd(&acc[(c0 & (NPB-1)) * D + 2*q],     w0 * bflo(u0));
        atomicAdd(&acc[(c0 & (NPB-1)) * D + 2*q + 1], w0 * bfhi(u0));
        atomicAdd(&acc[(c1 & (NPB-1)) * D + 2*q],     w1 * bflo(u1));
        atomicAdd(&acc[(c1 & (NPB-1)) * D + 2*q + 1], w1 * bfhi(u1));
        atomicAdd(&acc[(c2 & (NPB-1)) * D + 2*q],     w2 * bflo(u2));
        atomicAdd(&acc[(c2 & (NPB-1)) * D + 2*q + 1], w2 * bfhi(u2));
        atomicAdd(&acc[(c3 & (NPB-1)) * D + 2*q],     w3 * bflo(u3));
        atomicAdd(&acc[(c3 & (NPB-1)) * D + 2*q + 1], w3 * bfhi(u3));
    }
    for (; j < cb; j += 4) {
        long long ll = bb[j];
        int r = (int)(ll >> 32), c = (int)(unsigned)ll;
        unsigned u = xbu[(size_t)r * 64 + q];
        float w = dis[r];
        atomicAdd(&acc[(c & (NPB-1)) * D + 2*q],     w * bflo(u));
        atomicAdd(&acc[(c & (NPB-1)) * D + 2*q + 1], w * bfhi(u));
    }

    int sc = min(*spillCnt, SPILL_MAX);
    for (int i2 = wid; i2 < sc; i2 += 4) {          // normally zero iterations
        long long ll = spill[i2];
        int c = (int)(unsigned)ll;
        if ((c >> BIN_SHIFT) != b) continue;
        int r = (int)(ll >> 32);
        unsigned u = xbu[(size_t)r * 64 + q];
        float w = dis[r];
        atomicAdd(&acc[(c & (NPB-1)) * D + 2*q],     w * bflo(u));
        atomicAdd(&acc[(c & (NPB-1)) * D + 2*q + 1], w * bfhi(u));
    }
    __syncthreads();

    // writeout: 64 nodes x 32 float4
    const vfloat4* bias4 = reinterpret_cast<const vfloat4*>(bias);
    vfloat4* out4 = reinterpret_cast<vfloat4*>(out);
    for (int i = t; i < NPB * 32; i += B) {
        int ln = i >> 5, qq = i & 31;
        int gn = b * NPB + ln;
        if (gn >= n) continue;
        float dc = dis[gn];
        vfloat4 av = reinterpret_cast<const vfloat4*>(acc)[i];
        uint2 xc2 = reinterpret_cast<const uint2*>(xbu)[(size_t)gn * 32 + qq];
        vfloat4 xcv = bf2f4(xc2.x, xc2.y);
        vfloat4 ov = bias4[qq] + dc * (av + dc * xcv);
        __builtin_nontemporal_store(ov, out4 + (size_t)gn * 32 + qq);
    }
}

// ======================= fallback: round-4 CSR pipeline =======================

__global__ void k_zero(int* __restrict__ degInt, int n) {
    int i = blockIdx.x * blockDim.x + threadIdx.x;
    if (i < n) degInt[i] = 0;
}

__global__ void k_count(const int* __restrict__ col, int* __restrict__ degInt, int e) {
    int i = blockIdx.x * blockDim.x + threadIdx.x;
    if (i < e) atomicAdd(&degInt[col[i]], 1);
}

__global__ void k_scan1(const int* __restrict__ degInt, int* __restrict__ off,
                        int* __restrict__ bsum, int n) {
    __shared__ int sm[B];
    int i = blockIdx.x * B + threadIdx.x;
    int v = (i < n) ? degInt[i] : 0;
    sm[threadIdx.x] = v;
    __syncthreads();
    for (int s = 1; s < B; s <<= 1) {
        int t = (threadIdx.x >= (unsigned)s) ? sm[threadIdx.x - s] : 0;
        __syncthreads();
        sm[threadIdx.x] += t;
        __syncthreads();
    }
    if (i < n) off[i] = sm[threadIdx.x] - v;
    if (threadIdx.x == B - 1) bsum[blockIdx.x] = sm[B - 1];
}

__global__ void k_scan2(int* __restrict__ bsum, int nb) {
    __shared__ int sm[B];
    int v = (threadIdx.x < (unsigned)nb) ? bsum[threadIdx.x] : 0;
    sm[threadIdx.x] = v;
    __syncthreads();
    for (int s = 1; s < B; s <<= 1) {
        int t = (threadIdx.x >= (unsigned)s) ? sm[threadIdx.x - s] : 0;
        __syncthreads();
        sm[threadIdx.x] += t;
        __syncthreads();
    }
    if (threadIdx.x < (unsigned)nb) bsum[threadIdx.x] = sm[threadIdx.x] - v;
}

__global__ void k_scan3(int* __restrict__ off, const int* __restrict__ bsum,
                        const int* __restrict__ degInt, float* __restrict__ dis,
                        int* __restrict__ cursor, int n, int e) {
    int i = blockIdx.x * B + threadIdx.x;
    if (i < n) {
        int o = off[i] + bsum[blockIdx.x];
        off[i] = o;
        cursor[i] = o;
        dis[i] = rsqrtf((float)degInt[i] + 1.0f);
    }
    if (i == 0) off[n] = e;
}

__global__ void k_place_pairs(const int* __restrict__ row, const int* __restrict__ col,
                              const float* __restrict__ dis, int* __restrict__ cursor,
                              int2* __restrict__ pairs, int e) {
    int i = blockIdx.x * blockDim.x + threadIdx.x;
    if (i >= e) return;
    int r = row[i];
    int c = col[i];
    float w = dis[r];
    int pos = atomicAdd(&cursor[c], 1);
    pairs[pos] = make_int2(r, __float_as_int(w));
}

__global__ void k_aggregate_pairs(const float* __restrict__ x, const float* __restrict__ bias,
                                  const float* __restrict__ dis, const int* __restrict__ off,
                                  const int2* __restrict__ pairs, float* __restrict__ out,
                                  float* __restrict__ out2, int n) {
    int gid = blockIdx.x * blockDim.x + threadIdx.x;
    if (gid >= n * 32) return;
    int node = gid >> 5;
    int q    = gid & 31;
    const vfloat4* x4 = reinterpret_cast<const vfloat4*>(x);
    int j   = off[node];
    int end = off[node + 1];
    vfloat4 a0 = {0.f, 0.f, 0.f, 0.f};
    vfloat4 a1 = a0, a2 = a0, a3 = a0;
    for (; j + 4 <= end; j += 4) {
        int2 p0 = pairs[j + 0];
        int2 p1 = pairs[j + 1];
        int2 p2 = pairs[j + 2];
        int2 p3 = pairs[j + 3];
        vfloat4 v0 = x4[(size_t)p0.x * 32 + q];
        vfloat4 v1 = x4[(size_t)p1.x * 32 + q];
        vfloat4 v2 = x4[(size_t)p2.x * 32 + q];
        vfloat4 v3 = x4[(size_t)p3.x * 32 + q];
        a0 += __int_as_float(p0.y) * v0;
        a1 += __int_as_float(p1.y) * v1;
        a2 += __int_as_float(p2.y) * v2;
        a3 += __int_as_float(p3.y) * v3;
    }
    for (; j < end; ++j) {
        int2 p = pairs[j];
        a0 += __int_as_float(p.y) * x4[(size_t)p.x * 32 + q];
    }
    float dc = dis[node];
    vfloat4 xc = x4[(size_t)node * 32 + q];
    vfloat4 bv = reinterpret_cast<const vfloat4*>(bias)[q];
    vfloat4 ov = bv + dc * (a0 + a1 + a2 + a3 + dc * xc);
    __builtin_nontemporal_store(ov, reinterpret_cast<vfloat4*>(out)  + (size_t)node * 32 + q);
    __builtin_nontemporal_store(xc, reinterpret_cast<vfloat4*>(out2) + (size_t)node * 32 + q);
}

// =============================================================================

extern "C" void kernel_launch(void* const* d_in, const int* in_sizes, int n_in,
                              void* d_out, int out_size, void* d_ws, size_t ws_size,
                              hipStream_t stream) {
    const float* x    = (const float*)d_in[0];
    const int*   idx  = (const int*)d_in[1];   // [2, E]
    const float* bias = (const float*)d_in[2];

    const int n = in_sizes[0] / D;             // 50000
    const int e = in_sizes[1] / 2;             // 600000

    const int* row = idx;                      // sources
    const int* col = idx + e;                  // destinations

    float* out  = (float*)d_out;                     // [n, 128]
    float* out2 = (float*)d_out + (size_t)n * D;     // init_embeds

    const int nbins = (n + NPB - 1) >> BIN_SHIFT;    // 782
    const int prepB = (n * 32 + B - 1) / B;
    const int nA    = (e + CHA - 1) / CHA;           // 147

    // ---- LDS-tile scatter layout ----
    char* p0 = (char*)d_ws;
    int*  gcur     = (int*)p0;                       p0 += (size_t)MAXBINS * 4;
    int*  spillCnt = (int*)p0;                       p0 += 16;
    long long* spill = (long long*)p0;               p0 += (size_t)SPILL_MAX * 8;
    float* dis     = (float*)p0;                     p0 += (size_t)n * 4;
    p0 = (char*)(((uintptr_t)p0 + 15) & ~(uintptr_t)15);
    uint2* xb      = (uint2*)p0;                     p0 += (size_t)n * 32 * 8;   // bf16 x
    p0 = (char*)(((uintptr_t)p0 + 15) & ~(uintptr_t)15);
    long long* gbin = (long long*)p0;                p0 += (size_t)nbins * CAPB * 8;
    size_t need_new = (size_t)(p0 - (char*)d_ws);

    if (ws_size >= need_new && nbins <= MAXBINS) {
        k_prep   <<<prepB, B, 0, stream>>>(x, out2, xb, gcur, spillCnt, n, nbins);
        k_bucketA<<<nA,    B, 0, stream>>>(row, col, gbin, gcur, spill, spillCnt, e, nbins);
        k_deg    <<<nbins, B, 0, stream>>>(gbin, gcur, spill, spillCnt, dis, n);
        k_aggB   <<<nbins, B, 0, stream>>>(xb, bias, dis, gbin, gcur, spill, spillCnt, out, n);
        return;
    }

    // ---- fallback: round-4 CSR pipeline ----
    char* p = (char*)d_ws;
    int*   degInt = (int*)p;            p += (size_t)n * 4;
    int*   cur2   = (int*)p;            p += (size_t)n * 4;
    int*   off    = (int*)p;            p += (size_t)(n + 1) * 4;
    int*   bsum   = (int*)p;            p += 256 * 4;
    float* disF   = (float*)p;          p += (size_t)n * 4;
    p = (char*)(((uintptr_t)p + 15) & ~(uintptr_t)15);
    int2*  pairs  = (int2*)p;

    const int nbN = (n + B - 1) / B;
    const int nbE = (e + B - 1) / B;
    const int aggB = (n * 32 + B - 1) / B;
    k_zero <<<nbN, B, 0, stream>>>(degInt, n);
    k_count<<<nbE, B, 0, stream>>>(col, degInt, e);
    k_scan1<<<nbN, B, 0, stream>>>(degInt, off, bsum, n);
    k_scan2<<<1,   B, 0, stream>>>(bsum, nbN);
    k_scan3<<<nbN, B, 0, stream>>>(off, bsum, degInt, disF, cur2, n, e);
    k_place_pairs<<<nbE, B, 0, stream>>>(row, col, disF, cur2, pairs, e);
    k_aggregate_pairs<<<aggB, B, 0, stream>>>(x, bias, disF, off, pairs, out, out2, n);
}

// Round 12
// 78.987 us; speedup vs baseline: 6.9185x; 6.9185x over previous
//
#include <hip/hip_runtime.h>

#define D 128
#define B 256
#define WMAX 64
#define SPILL_MAX 8192
#define NPART 8            // XCD count; blockIdx % 8 ~ XCD (perf heuristic only)
#define PLACE_BLOCKS 2048  // 8 groups x 256 blocks

typedef float vfloat4 __attribute__((ext_vector_type(4)));

// ---------------------------------------------------------------------------
// GCN message passing, ELL + bf16 gather (round-7 structure) + fused build:
//   zero : cursor = 0, spillCnt = 0
//   mega : block-role split —
//          blocks [0, 2048): XCD-partitioned place (group p keeps dests in
//            [n*p/8, n*(p+1)/8); cursor atomic + ssrc store stay XCD-local)
//          blocks [2048, ...): prep (out2 = x via NT store, xb = bf16(x))
//          Roles touch disjoint memory; place overlaps under prep's BW use.
//   agg  : 32 lanes/node, 8B bf16 gathers, x4 unroll; spill folded in;
//          out[c] = bias + dc*( sum_j rsqrt(deg_rj+1)*xb[r_j] + dc*xb[c] )
// Fallback (small ws): round-4 CSR-pairs pipeline (known good).
// ---------------------------------------------------------------------------

__device__ __forceinline__ unsigned short f2bf(float f) {   // RTNE f32->bf16
    unsigned u = __float_as_uint(f);
    u = u + 0x7FFFu + ((u >> 16) & 1u);
    return (unsigned short)(u >> 16);
}

__device__ __forceinline__ vfloat4 bf2f4(unsigned lo, unsigned hi) {
    vfloat4 r;
    r.x = __uint_as_float(lo << 16);
    r.y = __uint_as_float(lo & 0xffff0000u);
    r.z = __uint_as_float(hi << 16);
    r.w = __uint_as_float(hi & 0xffff0000u);
    return r;
}

__global__ void k_zero2(int* __restrict__ cursor, int* __restrict__ spillCnt, int n) {
    int i = blockIdx.x * blockDim.x + threadIdx.x;
    if (i == 0) *spillCnt = 0;
    if (i < n) cursor[i] = 0;
}

// Fused place + prep. Place blocks first (start latency chains early).
__global__ void k_mega(const float* __restrict__ x, float* __restrict__ out2,
                       uint2* __restrict__ xb,
                       const int* __restrict__ row, const int* __restrict__ col,
                       int* __restrict__ cursor, int* __restrict__ ssrc,
                       int2* __restrict__ spill, int* __restrict__ spillCnt,
                       int e, int n) {
    int bid = blockIdx.x;
    int t   = threadIdx.x;

    if (bid < PLACE_BLOCKS) {
        // ---- place role: group p scans all edges, keeps its node range ----
        int p  = bid & (NPART - 1);
        int bg = bid >> 3;
        int tg = bg * B + t;
        int T  = (PLACE_BLOCKS >> 3) * B;
        int lo = (int)((long long)n * p / NPART);
        int hi = (int)((long long)n * (p + 1) / NPART);

        for (int i = tg; i < e; i += T) {
            int c = col[i];
            if (c < lo || c >= hi) continue;
            int r = row[i];
            int pos = atomicAdd(&cursor[c], 1);
            if (pos < WMAX) {
                ssrc[c * WMAX + pos] = r;
            } else {
                int s = atomicAdd(spillCnt, 1);
                if (s < SPILL_MAX) spill[s] = make_int2(r, c);
            }
        }
    } else {
        // ---- prep role: out2 = x (NT), xb = bf16(x) ----
        int gid = (bid - PLACE_BLOCKS) * B + t;
        if (gid >= n * 32) return;
        vfloat4 xv = reinterpret_cast<const vfloat4*>(x)[gid];
        __builtin_nontemporal_store(xv, reinterpret_cast<vfloat4*>(out2) + gid);
        uint2 b;
        b.x = (unsigned)f2bf(xv.x) | ((unsigned)f2bf(xv.y) << 16);
        b.y = (unsigned)f2bf(xv.z) | ((unsigned)f2bf(xv.w) << 16);
        xb[gid] = b;
    }
}

// 32 lanes per node, 8B bf16 gather per lane, x4 unrolled; spill folded in.
// Partition mapping matches place's [n*p/8, n*(p+1)/8) ranges.
__global__ void k_agg_ell(const uint2* __restrict__ xb, const float* __restrict__ bias,
                          const int* __restrict__ cursor, const int* __restrict__ ssrc,
                          const int2* __restrict__ spill, const int* __restrict__ spillCnt,
                          float* __restrict__ out, int n) {
    int p  = blockIdx.x & (NPART - 1);
    int bg = blockIdx.x >> 3;
    int lo = (int)((long long)n * p / NPART);
    int hi = (int)((long long)n * (p + 1) / NPART);
    int node = lo + bg * 8 + (threadIdx.x >> 5);     // 8 nodes per block
    if (node >= hi) return;
    int q = threadIdx.x & 31;

    int cnt = cursor[node];
    int m   = min(cnt, WMAX);
    const int* sp = ssrc + node * WMAX;

    vfloat4 a0 = {0.f, 0.f, 0.f, 0.f};
    vfloat4 a1 = a0, a2 = a0, a3 = a0;

    int j = 0;
    for (; j + 4 <= m; j += 4) {
        int r0 = sp[j + 0], r1 = sp[j + 1], r2 = sp[j + 2], r3 = sp[j + 3];
        uint2 v0 = xb[(size_t)r0 * 32 + q];
        uint2 v1 = xb[(size_t)r1 * 32 + q];
        uint2 v2 = xb[(size_t)r2 * 32 + q];
        uint2 v3 = xb[(size_t)r3 * 32 + q];
        float w0 = rsqrtf((float)cursor[r0] + 1.0f);
        float w1 = rsqrtf((float)cursor[r1] + 1.0f);
        float w2 = rsqrtf((float)cursor[r2] + 1.0f);
        float w3 = rsqrtf((float)cursor[r3] + 1.0f);
        a0 += w0 * bf2f4(v0.x, v0.y);
        a1 += w1 * bf2f4(v1.x, v1.y);
        a2 += w2 * bf2f4(v2.x, v2.y);
        a3 += w3 * bf2f4(v3.x, v3.y);
    }
    for (; j < m; ++j) {
        int r = sp[j];
        uint2 v = xb[(size_t)r * 32 + q];
        float w = rsqrtf((float)cursor[r] + 1.0f);
        a0 += w * bf2f4(v.x, v.y);
    }

    // Overflow edges (normally zero): scan the tiny spill list.
    if (cnt > WMAX) {
        int sc = min(*spillCnt, SPILL_MAX);
        for (int s = 0; s < sc; ++s) {
            int2 pr = spill[s];
            if (pr.y == node) {
                float w = rsqrtf((float)cursor[pr.x] + 1.0f);
                uint2 v = xb[(size_t)pr.x * 32 + q];
                a0 += w * bf2f4(v.x, v.y);
            }
        }
    }

    float dc = rsqrtf((float)cnt + 1.0f);
    uint2 xc2 = xb[(size_t)node * 32 + q];
    vfloat4 xc = bf2f4(xc2.x, xc2.y);
    vfloat4 bv = reinterpret_cast<const vfloat4*>(bias)[q];
    vfloat4 ov = bv + dc * (a0 + a1 + a2 + a3 + dc * xc);

    __builtin_nontemporal_store(ov, reinterpret_cast<vfloat4*>(out) + (size_t)node * 32 + q);
}

// ======================= fallback: round-4 CSR pipeline =======================

__global__ void k_zero(int* __restrict__ degInt, int n) {
    int i = blockIdx.x * blockDim.x + threadIdx.x;
    if (i < n) degInt[i] = 0;
}

__global__ void k_count(const int* __restrict__ col, int* __restrict__ degInt, int e) {
    int i = blockIdx.x * blockDim.x + threadIdx.x;
    if (i < e) atomicAdd(&degInt[col[i]], 1);
}

__global__ void k_scan1(const int* __restrict__ degInt, int* __restrict__ off,
                        int* __restrict__ bsum, int n) {
    __shared__ int sm[B];
    int i = blockIdx.x * B + threadIdx.x;
    int v = (i < n) ? degInt[i] : 0;
    sm[threadIdx.x] = v;
    __syncthreads();
    for (int s = 1; s < B; s <<= 1) {
        int t = (threadIdx.x >= (unsigned)s) ? sm[threadIdx.x - s] : 0;
        __syncthreads();
        sm[threadIdx.x] += t;
        __syncthreads();
    }
    if (i < n) off[i] = sm[threadIdx.x] - v;
    if (threadIdx.x == B - 1) bsum[blockIdx.x] = sm[B - 1];
}

__global__ void k_scan2(int* __restrict__ bsum, int nb) {
    __shared__ int sm[B];
    int v = (threadIdx.x < (unsigned)nb) ? bsum[threadIdx.x] : 0;
    sm[threadIdx.x] = v;
    __syncthreads();
    for (int s = 1; s < B; s <<= 1) {
        int t = (threadIdx.x >= (unsigned)s) ? sm[threadIdx.x - s] : 0;
        __syncthreads();
        sm[threadIdx.x] += t;
        __syncthreads();
    }
    if (threadIdx.x < (unsigned)nb) bsum[threadIdx.x] = sm[threadIdx.x] - v;
}

__global__ void k_scan3(int* __restrict__ off, const int* __restrict__ bsum,
                        const int* __restrict__ degInt, float* __restrict__ dis,
                        int* __restrict__ cursor, int n, int e) {
    int i = blockIdx.x * B + threadIdx.x;
    if (i < n) {
        int o = off[i] + bsum[blockIdx.x];
        off[i] = o;
        cursor[i] = o;
        dis[i] = rsqrtf((float)degInt[i] + 1.0f);
    }
    if (i == 0) off[n] = e;
}

__global__ void k_place_pairs(const int* __restrict__ row, const int* __restrict__ col,
                              const float* __restrict__ dis, int* __restrict__ cursor,
                              int2* __restrict__ pairs, int e) {
    int i = blockIdx.x * blockDim.x + threadIdx.x;
    if (i >= e) return;
    int r = row[i];
    int c = col[i];
    float w = dis[r];
    int pos = atomicAdd(&cursor[c], 1);
    pairs[pos] = make_int2(r, __float_as_int(w));
}

__global__ void k_aggregate_pairs(const float* __restrict__ x, const float* __restrict__ bias,
                                  const float* __restrict__ dis, const int* __restrict__ off,
                                  const int2* __restrict__ pairs, float* __restrict__ out,
                                  float* __restrict__ out2, int n) {
    int gid = blockIdx.x * blockDim.x + threadIdx.x;
    if (gid >= n * 32) return;
    int node = gid >> 5;
    int q    = gid & 31;
    const vfloat4* x4 = reinterpret_cast<const vfloat4*>(x);
    int j   = off[node];
    int end = off[node + 1];
    vfloat4 a0 = {0.f, 0.f, 0.f, 0.f};
    vfloat4 a1 = a0, a2 = a0, a3 = a0;
    for (; j + 4 <= end; j += 4) {
        int2 p0 = pairs[j + 0];
        int2 p1 = pairs[j + 1];
        int2 p2 = pairs[j + 2];
        int2 p3 = pairs[j + 3];
        vfloat4 v0 = x4[(size_t)p0.x * 32 + q];
        vfloat4 v1 = x4[(size_t)p1.x * 32 + q];
        vfloat4 v2 = x4[(size_t)p2.x * 32 + q];
        vfloat4 v3 = x4[(size_t)p3.x * 32 + q];
        a0 += __int_as_float(p0.y) * v0;
        a1 += __int_as_float(p1.y) * v1;
        a2 += __int_as_float(p2.y) * v2;
        a3 += __int_as_float(p3.y) * v3;
    }
    for (; j < end; ++j) {
        int2 p = pairs[j];
        a0 += __int_as_float(p.y) * x4[(size_t)p.x * 32 + q];
    }
    float dc = dis[node];
    vfloat4 xc = x4[(size_t)node * 32 + q];
    vfloat4 bv = reinterpret_cast<const vfloat4*>(bias)[q];
    vfloat4 ov = bv + dc * (a0 + a1 + a2 + a3 + dc * xc);
    __builtin_nontemporal_store(ov, reinterpret_cast<vfloat4*>(out)  + (size_t)node * 32 + q);
    __builtin_nontemporal_store(xc, reinterpret_cast<vfloat4*>(out2) + (size_t)node * 32 + q);
}

// =============================================================================

extern "C" void kernel_launch(void* const* d_in, const int* in_sizes, int n_in,
                              void* d_out, int out_size, void* d_ws, size_t ws_size,
                              hipStream_t stream) {
    const float* x    = (const float*)d_in[0];
    const int*   idx  = (const int*)d_in[1];   // [2, E]
    const float* bias = (const float*)d_in[2];

    const int n = in_sizes[0] / D;             // 50000
    const int e = in_sizes[1] / 2;             // 600000

    const int* row = idx;                      // sources
    const int* col = idx + e;                  // destinations

    float* out  = (float*)d_out;                     // [n, 128]
    float* out2 = (float*)d_out + (size_t)n * D;     // init_embeds

    const int nbN  = (n + B - 1) / B;
    const int nbE  = (e + B - 1) / B;
    const int prepB = (n * 32 + B - 1) / B;          // 6250

    // ---- ELL + bf16 layout (round-7) ----
    char* p0 = (char*)d_ws;
    int*  cursor  = (int*)p0;                        p0 += (size_t)n * 4;
    int*  spillCnt= (int*)p0;                        p0 += 16;
    int2* spill   = (int2*)p0;                       p0 += (size_t)SPILL_MAX * 8;
    p0 = (char*)(((uintptr_t)p0 + 15) & ~(uintptr_t)15);
    uint2* xb     = (uint2*)p0;                      p0 += (size_t)n * 32 * 8;   // bf16 x
    int*  ssrc    = (int*)p0;                        p0 += (size_t)n * WMAX * 4;
    size_t need_ell = (size_t)(p0 - (char*)d_ws);

    if (ws_size >= need_ell) {
        int maxPart = 0;
        for (int p = 0; p < NPART; ++p) {
            int lo = (int)((long long)n * p / NPART);
            int hi = (int)((long long)n * (p + 1) / NPART);
            if (hi - lo > maxPart) maxPart = hi - lo;
        }
        const int bpg = (maxPart + 7) / 8;             // 8 nodes per block
        const int agB = bpg * NPART;
        const int megaB = PLACE_BLOCKS + prepB;

        k_zero2  <<<nbN,   B, 0, stream>>>(cursor, spillCnt, n);
        k_mega   <<<megaB, B, 0, stream>>>(x, out2, xb, row, col, cursor, ssrc,
                                           spill, spillCnt, e, n);
        k_agg_ell<<<agB,   B, 0, stream>>>(xb, bias, cursor, ssrc, spill, spillCnt, out, n);
        return;
    }

    // ---- fallback: round-4 CSR pipeline ----
    char* p = (char*)d_ws;
    int*   degInt = (int*)p;            p += (size_t)n * 4;
    int*   cur2   = (int*)p;            p += (size_t)n * 4;
    int*   off    = (int*)p;            p += (size_t)(n + 1) * 4;
    int*   bsum   = (int*)p;            p += 256 * 4;
    float* dis    = (float*)p;          p += (size_t)n * 4;
    p = (char*)(((uintptr_t)p + 15) & ~(uintptr_t)15);
    int2*  pairs  = (int2*)p;

    const int aggB = (n * 32 + B - 1) / B;
    k_zero <<<nbN, B, 0, stream>>>(degInt, n);
    k_count<<<nbE, B, 0, stream>>>(col, degInt, e);
    k_scan1<<<nbN, B, 0, stream>>>(degInt, off, bsum, n);
    k_scan2<<<1,   B, 0, stream>>>(bsum, nbN);
    k_scan3<<<nbN, B, 0, stream>>>(off, bsum, degInt, dis, cur2, n, e);
    k_place_pairs<<<nbE, B, 0, stream>>>(row, col, dis, cur2, pairs, e);
    k_aggregate_pairs<<<aggB, B, 0, stream>>>(x, bias, dis, off, pairs, out, out2, n);
}

// Round 13
// 77.574 us; speedup vs baseline: 7.0445x; 1.0182x over previous
//
#include <hip/hip_runtime.h>

#define D 128
#define B 256
#define WMAX 64
#define SPILL_MAX 8192
#define NPART 8   // XCD count on MI355X; blockIdx % 8 ~ XCD (perf heuristic only)

typedef float vfloat4 __attribute__((ext_vector_type(4)));

// ---------------------------------------------------------------------------
// GCN message passing, ELL + bf16-gather + XCD-partitioned build (round-7
// structure; agg inner loop deepened to 8-wide batches for gather MLP):
//   prep : cursor=0, out2=x (NT), xb=bf16(x)
//   place: 8 block-groups (one per XCD); group p scans ALL edges, keeps only
//          destinations in [n*p/8, n*(p+1)/8) -> cursor atomics and ssrc
//          stores stay in that XCD's L2.
//   agg  : 32 lanes/node, 8B bf16 gathers, 8-deep batches; spill folded in;
//          out[c] = bias + dc*( sum_j rsqrt(deg_rj+1)*xb[r_j] + dc*xb[c] )
// Fallback (small ws): round-4 CSR-pairs pipeline.
// ---------------------------------------------------------------------------

__device__ __forceinline__ unsigned short f2bf(float f) {   // RTNE f32->bf16
    unsigned u = __float_as_uint(f);
    u = u + 0x7FFFu + ((u >> 16) & 1u);
    return (unsigned short)(u >> 16);
}

__device__ __forceinline__ vfloat4 bf2f4(unsigned lo, unsigned hi) {
    vfloat4 r;
    r.x = __uint_as_float(lo << 16);
    r.y = __uint_as_float(lo & 0xffff0000u);
    r.z = __uint_as_float(hi << 16);
    r.w = __uint_as_float(hi & 0xffff0000u);
    return r;
}

__global__ void k_prep(const float* __restrict__ x, float* __restrict__ out2,
                       uint2* __restrict__ xb, int* __restrict__ cursor,
                       int* __restrict__ spillCnt, int n) {
    int gid = blockIdx.x * blockDim.x + threadIdx.x;
    if (gid == 0) *spillCnt = 0;
    if (gid < n) cursor[gid] = 0;
    if (gid >= n * 32) return;
    vfloat4 xv = reinterpret_cast<const vfloat4*>(x)[gid];
    __builtin_nontemporal_store(xv, reinterpret_cast<vfloat4*>(out2) + gid);
    uint2 b;
    b.x = (unsigned)f2bf(xv.x) | ((unsigned)f2bf(xv.y) << 16);
    b.y = (unsigned)f2bf(xv.z) | ((unsigned)f2bf(xv.w) << 16);
    xb[gid] = b;
}

// Group p (= blockIdx%8, tracking XCD round-robin) scans the whole edge list
// and places only destinations in its node range.
__global__ void k_place_ell(const int* __restrict__ row, const int* __restrict__ col,
                            int* __restrict__ cursor, int* __restrict__ ssrc,
                            int2* __restrict__ spill, int* __restrict__ spillCnt,
                            int e, int n) {
    int p  = blockIdx.x & (NPART - 1);
    int bg = blockIdx.x >> 3;                       // block index within group
    int tg = bg * blockDim.x + threadIdx.x;         // thread index within group
    int T  = (gridDim.x >> 3) * blockDim.x;         // threads per group
    int lo = (int)((long long)n * p / NPART);
    int hi = (int)((long long)n * (p + 1) / NPART);

    for (int i = tg; i < e; i += T) {
        int c = col[i];
        if (c < lo || c >= hi) continue;
        int r = row[i];
        int pos = atomicAdd(&cursor[c], 1);
        if (pos < WMAX) {
            ssrc[c * WMAX + pos] = r;
        } else {
            int s = atomicAdd(spillCnt, 1);
            if (s < SPILL_MAX) spill[s] = make_int2(r, c);
        }
    }
}

// 32 lanes per node; 8-deep gather batches (8 xb loads in flight per lane).
__global__ void k_agg_ell(const uint2* __restrict__ xb, const float* __restrict__ bias,
                          const int* __restrict__ cursor, const int* __restrict__ ssrc,
                          const int2* __restrict__ spill, const int* __restrict__ spillCnt,
                          float* __restrict__ out, int n) {
    int p  = blockIdx.x & (NPART - 1);
    int bg = blockIdx.x >> 3;
    int lo = (int)((long long)n * p / NPART);
    int hi = (int)((long long)n * (p + 1) / NPART);
    int node = lo + bg * 8 + (threadIdx.x >> 5);     // 8 nodes per block
    if (node >= hi) return;
    int q = threadIdx.x & 31;

    int cnt = cursor[node];
    int m   = min(cnt, WMAX);
    const int* sp = ssrc + node * WMAX;

    vfloat4 a0 = {0.f, 0.f, 0.f, 0.f};
    vfloat4 a1 = a0, a2 = a0, a3 = a0;

    int j = 0;
    // 8-deep batch: 8 independent gathers in flight per lane.
    for (; j + 8 <= m; j += 8) {
        int r0 = sp[j+0], r1 = sp[j+1], r2 = sp[j+2], r3 = sp[j+3];
        int r4_ = sp[j+4], r5 = sp[j+5], r6 = sp[j+6], r7 = sp[j+7];
        uint2 v0 = xb[(size_t)r0 * 32 + q];
        uint2 v1 = xb[(size_t)r1 * 32 + q];
        uint2 v2 = xb[(size_t)r2 * 32 + q];
        uint2 v3 = xb[(size_t)r3 * 32 + q];
        uint2 v4 = xb[(size_t)r4_ * 32 + q];
        uint2 v5 = xb[(size_t)r5 * 32 + q];
        uint2 v6 = xb[(size_t)r6 * 32 + q];
        uint2 v7 = xb[(size_t)r7 * 32 + q];
        float w0 = rsqrtf((float)cursor[r0] + 1.0f);
        float w1 = rsqrtf((float)cursor[r1] + 1.0f);
        float w2 = rsqrtf((float)cursor[r2] + 1.0f);
        float w3 = rsqrtf((float)cursor[r3] + 1.0f);
        float w4 = rsqrtf((float)cursor[r4_] + 1.0f);
        float w5 = rsqrtf((float)cursor[r5] + 1.0f);
        float w6 = rsqrtf((float)cursor[r6] + 1.0f);
        float w7 = rsqrtf((float)cursor[r7] + 1.0f);
        a0 += w0 * bf2f4(v0.x, v0.y);
        a1 += w1 * bf2f4(v1.x, v1.y);
        a2 += w2 * bf2f4(v2.x, v2.y);
        a3 += w3 * bf2f4(v3.x, v3.y);
        a0 += w4 * bf2f4(v4.x, v4.y);
        a1 += w5 * bf2f4(v5.x, v5.y);
        a2 += w6 * bf2f4(v6.x, v6.y);
        a3 += w7 * bf2f4(v7.x, v7.y);
    }
    for (; j + 4 <= m; j += 4) {
        int r0 = sp[j+0], r1 = sp[j+1], r2 = sp[j+2], r3 = sp[j+3];
        uint2 v0 = xb[(size_t)r0 * 32 + q];
        uint2 v1 = xb[(size_t)r1 * 32 + q];
        uint2 v2 = xb[(size_t)r2 * 32 + q];
        uint2 v3 = xb[(size_t)r3 * 32 + q];
        float w0 = rsqrtf((float)cursor[r0] + 1.0f);
        float w1 = rsqrtf((float)cursor[r1] + 1.0f);
        float w2 = rsqrtf((float)cursor[r2] + 1.0f);
        float w3 = rsqrtf((float)cursor[r3] + 1.0f);
        a0 += w0 * bf2f4(v0.x, v0.y);
        a1 += w1 * bf2f4(v1.x, v1.y);
        a2 += w2 * bf2f4(v2.x, v2.y);
        a3 += w3 * bf2f4(v3.x, v3.y);
    }
    for (; j < m; ++j) {
        int r = sp[j];
        uint2 v = xb[(size_t)r * 32 + q];
        float w = rsqrtf((float)cursor[r] + 1.0f);
        a0 += w * bf2f4(v.x, v.y);
    }

    // Overflow edges (normally zero): scan the tiny spill list.
    if (cnt > WMAX) {
        int sc = min(*spillCnt, SPILL_MAX);
        for (int s = 0; s < sc; ++s) {
            int2 pr = spill[s];
            if (pr.y == node) {
                float w = rsqrtf((float)cursor[pr.x] + 1.0f);
                uint2 v = xb[(size_t)pr.x * 32 + q];
                a0 += w * bf2f4(v.x, v.y);
            }
        }
    }

    float dc = rsqrtf((float)cnt + 1.0f);
    uint2 xc2 = xb[(size_t)node * 32 + q];
    vfloat4 xc = bf2f4(xc2.x, xc2.y);
    vfloat4 bv = reinterpret_cast<const vfloat4*>(bias)[q];
    vfloat4 ov = bv + dc * (a0 + a1 + a2 + a3 + dc * xc);

    __builtin_nontemporal_store(ov, reinterpret_cast<vfloat4*>(out) + (size_t)node * 32 + q);
}

// ======================= fallback: round-4 CSR pipeline =======================

__global__ void k_zero(int* __restrict__ degInt, int n) {
    int i = blockIdx.x * blockDim.x + threadIdx.x;
    if (i < n) degInt[i] = 0;
}

__global__ void k_count(const int* __restrict__ col, int* __restrict__ degInt, int e) {
    int i = blockIdx.x * blockDim.x + threadIdx.x;
    if (i < e) atomicAdd(&degInt[col[i]], 1);
}

__global__ void k_scan1(const int* __restrict__ degInt, int* __restrict__ off,
                        int* __restrict__ bsum, int n) {
    __shared__ int sm[B];
    int i = blockIdx.x * B + threadIdx.x;
    int v = (i < n) ? degInt[i] : 0;
    sm[threadIdx.x] = v;
    __syncthreads();
    for (int s = 1; s < B; s <<= 1) {
        int t = (threadIdx.x >= (unsigned)s) ? sm[threadIdx.x - s] : 0;
        __syncthreads();
        sm[threadIdx.x] += t;
        __syncthreads();
    }
    if (i < n) off[i] = sm[threadIdx.x] - v;
    if (threadIdx.x == B - 1) bsum[blockIdx.x] = sm[B - 1];
}

__global__ void k_scan2(int* __restrict__ bsum, int nb) {
    __shared__ int sm[B];
    int v = (threadIdx.x < (unsigned)nb) ? bsum[threadIdx.x] : 0;
    sm[threadIdx.x] = v;
    __syncthreads();
    for (int s = 1; s < B; s <<= 1) {
        int t = (threadIdx.x >= (unsigned)s) ? sm[threadIdx.x - s] : 0;
        __syncthreads();
        sm[threadIdx.x] += t;
        __syncthreads();
    }
    if (threadIdx.x < (unsigned)nb) bsum[threadIdx.x] = sm[threadIdx.x] - v;
}

__global__ void k_scan3(int* __restrict__ off, const int* __restrict__ bsum,
                        const int* __restrict__ degInt, float* __restrict__ dis,
                        int* __restrict__ cursor, int n, int e) {
    int i = blockIdx.x * B + threadIdx.x;
    if (i < n) {
        int o = off[i] + bsum[blockIdx.x];
        off[i] = o;
        cursor[i] = o;
        dis[i] = rsqrtf((float)degInt[i] + 1.0f);
    }
    if (i == 0) off[n] = e;
}

__global__ void k_place_pairs(const int* __restrict__ row, const int* __restrict__ col,
                              const float* __restrict__ dis, int* __restrict__ cursor,
                              int2* __restrict__ pairs, int e) {
    int i = blockIdx.x * blockDim.x + threadIdx.x;
    if (i >= e) return;
    int r = row[i];
    int c = col[i];
    float w = dis[r];
    int pos = atomicAdd(&cursor[c], 1);
    pairs[pos] = make_int2(r, __float_as_int(w));
}

__global__ void k_aggregate_pairs(const float* __restrict__ x, const float* __restrict__ bias,
                                  const float* __restrict__ dis, const int* __restrict__ off,
                                  const int2* __restrict__ pairs, float* __restrict__ out,
                                  float* __restrict__ out2, int n) {
    int gid = blockIdx.x * blockDim.x + threadIdx.x;
    if (gid >= n * 32) return;
    int node = gid >> 5;
    int q    = gid & 31;
    const vfloat4* x4 = reinterpret_cast<const vfloat4*>(x);
    int j   = off[node];
    int end = off[node + 1];
    vfloat4 a0 = {0.f, 0.f, 0.f, 0.f};
    vfloat4 a1 = a0, a2 = a0, a3 = a0;
    for (; j + 4 <= end; j += 4) {
        int2 p0 = pairs[j + 0];
        int2 p1 = pairs[j + 1];
        int2 p2 = pairs[j + 2];
        int2 p3 = pairs[j + 3];
        vfloat4 v0 = x4[(size_t)p0.x * 32 + q];
        vfloat4 v1 = x4[(size_t)p1.x * 32 + q];
        vfloat4 v2 = x4[(size_t)p2.x * 32 + q];
        vfloat4 v3 = x4[(size_t)p3.x * 32 + q];
        a0 += __int_as_float(p0.y) * v0;
        a1 += __int_as_float(p1.y) * v1;
        a2 += __int_as_float(p2.y) * v2;
        a3 += __int_as_float(p3.y) * v3;
    }
    for (; j < end; ++j) {
        int2 p = pairs[j];
        a0 += __int_as_float(p.y) * x4[(size_t)p.x * 32 + q];
    }
    float dc = dis[node];
    vfloat4 xc = x4[(size_t)node * 32 + q];
    vfloat4 bv = reinterpret_cast<const vfloat4*>(bias)[q];
    vfloat4 ov = bv + dc * (a0 + a1 + a2 + a3 + dc * xc);
    __builtin_nontemporal_store(ov, reinterpret_cast<vfloat4*>(out)  + (size_t)node * 32 + q);
    __builtin_nontemporal_store(xc, reinterpret_cast<vfloat4*>(out2) + (size_t)node * 32 + q);
}

// =============================================================================

extern "C" void kernel_launch(void* const* d_in, const int* in_sizes, int n_in,
                              void* d_out, int out_size, void* d_ws, size_t ws_size,
                              hipStream_t stream) {
    const float* x    = (const float*)d_in[0];
    const int*   idx  = (const int*)d_in[1];   // [2, E]
    const float* bias = (const float*)d_in[2];

    const int n = in_sizes[0] / D;             // 50000
    const int e = in_sizes[1] / 2;             // 600000

    const int* row = idx;                      // sources
    const int* col = idx + e;                  // destinations

    float* out  = (float*)d_out;                     // [n, 128]
    float* out2 = (float*)d_out + (size_t)n * D;     // init_embeds

    const int nbN = (n + B - 1) / B;
    const int nbE = (e + B - 1) / B;
    const int prepB = (n * 32 + B - 1) / B;

    // ---- ELL + bf16 layout ----
    char* p0 = (char*)d_ws;
    int*  cursor  = (int*)p0;                        p0 += (size_t)n * 4;
    int*  spillCnt= (int*)p0;                        p0 += 16;
    int2* spill   = (int2*)p0;                       p0 += (size_t)SPILL_MAX * 8;
    p0 = (char*)(((uintptr_t)p0 + 15) & ~(uintptr_t)15);
    uint2* xb     = (uint2*)p0;                      p0 += (size_t)n * 32 * 8;   // bf16 x
    int*  ssrc    = (int*)p0;                        p0 += (size_t)n * WMAX * 4;
    size_t need_ell = (size_t)(p0 - (char*)d_ws);

    if (ws_size >= need_ell) {
        const int plB = 2048;   // 8 XCD groups x 256 blocks, all co-resident
        int maxPart = 0;
        for (int p = 0; p < NPART; ++p) {
            int lo = (int)((long long)n * p / NPART);
            int hi = (int)((long long)n * (p + 1) / NPART);
            if (hi - lo > maxPart) maxPart = hi - lo;
        }
        const int bpg = (maxPart + 7) / 8;             // 8 nodes per block
        const int agB = bpg * NPART;
        k_prep     <<<prepB, B, 0, stream>>>(x, out2, xb, cursor, spillCnt, n);
        k_place_ell<<<plB,   B, 0, stream>>>(row, col, cursor, ssrc, spill, spillCnt, e, n);
        k_agg_ell  <<<agB,   B, 0, stream>>>(xb, bias, cursor, ssrc, spill, spillCnt, out, n);
        return;
    }

    // ---- fallback: round-4 CSR pipeline ----
    char* p = (char*)d_ws;
    int*   degInt = (int*)p;            p += (size_t)n * 4;
    int*   cur2   = (int*)p;            p += (size_t)n * 4;
    int*   off    = (int*)p;            p += (size_t)(n + 1) * 4;
    int*   bsum   = (int*)p;            p += 256 * 4;
    float* dis    = (float*)p;          p += (size_t)n * 4;
    p = (char*)(((uintptr_t)p + 15) & ~(uintptr_t)15);
    int2*  pairs  = (int2*)p;

    const int aggB = (n * 32 + B - 1) / B;
    k_zero <<<nbN, B, 0, stream>>>(degInt, n);
    k_count<<<nbE, B, 0, stream>>>(col, degInt, e);
    k_scan1<<<nbN, B, 0, stream>>>(degInt, off, bsum, n);
    k_scan2<<<1,   B, 0, stream>>>(bsum, nbN);
    k_scan3<<<nbN, B, 0, stream>>>(off, bsum, degInt, dis, cur2, n, e);
    k_place_pairs<<<nbE, B, 0, stream>>>(row, col, dis, cur2, pairs, e);
    k_aggregate_pairs<<<aggB, B, 0, stream>>>(x, bias, dis, off, pairs, out, out2, n);
}